// Round 2
// baseline (296.315 us; speedup 1.0000x reference)
//
#include <hip/hip_runtime.h>

// Reference output: jax.nn.softmax(attn, axis=-1) where attn is [B,T,1].
// Softmax over a singleton axis is exp(a-a)/1 == 1.0f for any finite a,
// and a is structurally finite (tanh in [-1,1], v in [0,1) => |attn| <= H).
// So the output is identically 1.0f: out_size = B*T = 65536 floats (256 KB).
// Optimal kernel = vectorized fill; launch-latency bound.

__global__ __launch_bounds__(256) void fill_ones_kernel(float4* __restrict__ out4,
                                                        int n4,
                                                        float* __restrict__ out,
                                                        int tail_start,
                                                        int n_tail) {
    int i = blockIdx.x * blockDim.x + threadIdx.x;
    if (i < n4) {
        out4[i] = make_float4(1.0f, 1.0f, 1.0f, 1.0f);
    }
    if (i < n_tail) {                 // empty when out_size % 4 == 0
        out[tail_start + i] = 1.0f;
    }
}

extern "C" void kernel_launch(void* const* d_in, const int* in_sizes, int n_in,
                              void* d_out, int out_size, void* d_ws, size_t ws_size,
                              hipStream_t stream) {
    (void)d_in; (void)in_sizes; (void)n_in; (void)d_ws; (void)ws_size;

    float* out = (float*)d_out;
    int n = out_size;            // 65536
    int n4 = n / 4;              // 16384 float4 stores
    int tail_start = n4 * 4;
    int n_tail = n - tail_start; // 0 for 65536

    int block = 256;
    int work = n4 > n_tail ? n4 : n_tail;
    int grid = (work + block - 1) / block;
    if (grid < 1) grid = 1;

    fill_ones_kernel<<<grid, block, 0, stream>>>(
        (float4*)out, n4, out, tail_start, n_tail);
}